// Round 6
// baseline (299.019 us; speedup 1.0000x reference)
//
#include <hip/hip_runtime.h>

#define IMW 512
#define NP 4096

#define DIST_BLOCKS 8                  // 1 block per batch, binned neighbor search (first in grid)
#define GATHER_BLOCKS 256              // 32768 points / 128 threads
#define TOTAL_BLOCKS (DIST_BLOCKS + GATHER_BLOCKS)
#define BS 128

#define NCELL 20                       // 20x20 grid of 0.05-sized cells
#define NCELL2 400
#define PPT 32                         // points per thread in dist blocks (4096/128)

// Gaussian kernel, sigma = 0.3*((11-1)*0.5 - 1) + 0.8 = 2.0, normalized (f64-accurate, rounded to f32)
__device__ constexpr float KW[11] = {
    0.00881223f, 0.02714359f, 0.06511407f, 0.12164908f, 0.17699836f,
    0.20056542f, 0.17699836f, 0.12164908f, 0.06511407f, 0.02714359f, 0.00881223f};

// reflect map: valid for r in [-5, 517]; matches both the blur pad and the intensity pad
__device__ __forceinline__ int refl(int r) {
    r = r < 0 ? -r : r;
    return r > 511 ? 1022 - r : r;
}

__device__ __forceinline__ int cell_of(float2 p) {
    const int cx = min((int)(p.x * 20.f), NCELL - 1);
    const int cy = min((int)(p.y * 20.f), NCELL - 1);
    return cy * NCELL + cx;
}

// blocks [0,8): dist-push via 20x20 binning (LDS counting sort, sorted-order neighbor phase)
// blocks [8,264): intensity gather w/ inline row-major 2D blur, 128 points per block
__global__ __launch_bounds__(BS)
void fused_compute(const float* __restrict__ trace, const float* __restrict__ img,
                   float* __restrict__ partials) {
    const int tid = threadIdx.x;
    const int bx = blockIdx.x;
    __shared__ float2 sorted[NP];      // 32 KB
    __shared__ int cellcnt[NCELL2];
    __shared__ int cellstart[NCELL2];
    __shared__ int cursor[NCELL2];
    __shared__ float red[2];
    float local;

    if (bx < DIST_BLOCKS) {
        // ---- dist push, spatially binned ----
        const int b = bx;
        const float2* tb = (const float2*)(trace + b * NP * 2);
        for (int i = tid; i < NCELL2; i += BS) cellcnt[i] = 0;
        __syncthreads();
        // histogram
#pragma unroll
        for (int k = 0; k < PPT; ++k) {
            const float2 pt = tb[tid + BS * k];
            atomicAdd(&cellcnt[cell_of(pt)], 1);
        }
        __syncthreads();
        // exclusive scan over 400 cells, single wave (7 chunks of 64, shfl scan)
        if (tid < 64) {
            int running = 0;
#pragma unroll
            for (int ch = 0; ch < 7; ++ch) {
                const int idx = ch * 64 + tid;
                const int v = (idx < NCELL2) ? cellcnt[idx] : 0;
                int incl = v;
#pragma unroll
                for (int s = 1; s < 64; s <<= 1) {
                    const int t = __shfl_up(incl, s, 64);
                    if (tid >= s) incl += t;
                }
                if (idx < NCELL2) {
                    const int st = running + incl - v;
                    cellstart[idx] = st;
                    cursor[idx] = st;
                }
                running += __shfl(incl, 63, 64);
            }
        }
        __syncthreads();
        // scatter into sorted order
#pragma unroll
        for (int k = 0; k < PPT; ++k) {
            const float2 pt = tb[tid + BS * k];
            const int pos = atomicAdd(&cursor[cell_of(pt)], 1);
            sorted[pos] = pt;
        }
        __syncthreads();
        // neighbor phase IN SORTED ORDER: a wave's 64 lanes hold 64 spatially-adjacent points
        // -> neighbor ranges overlap -> sorted[q] reads are near-broadcast, bounds near-uniform
        float s = 0.f;
#pragma unroll 4
        for (int k = 0; k < PPT; ++k) {
            const float2 p = sorted[tid + BS * k];
            const int c = cell_of(p);
            const int cy = c / NCELL, cx = c - cy * NCELL;
            const int x0 = max(cx - 1, 0), x1 = min(cx + 1, NCELL - 1);
            const int y0 = max(cy - 1, 0), y1 = min(cy + 1, NCELL - 1);
            for (int ny = y0; ny <= y1; ++ny) {
                const int rb = ny * NCELL;
                int q = cellstart[rb + x0];
                const int qe = cellstart[rb + x1] + cellcnt[rb + x1];
                for (; q < qe; ++q) {
                    const float2 o = sorted[q];
                    const float dx = p.x - o.x, dy = p.y - o.y;
                    const float d2 = fmaf(dx, dx, dy * dy);
                    // self-pair contributes exactly 0.05; subtracted analytically in finalize
                    s += (d2 < 0.0025f) ? (0.05f - __builtin_amdgcn_sqrtf(d2)) : 0.f;
                }
            }
        }
        local = s;
    } else {
        // ---- intensity gather: one point per thread, row-major window walk ----
        const int p = (bx - DIST_BLOCKS) * BS + tid;   // [0, 32768)
        const int b = p >> 12;
        const float2 t2 = ((const float2*)trace)[b * NP + (p & (NP - 1))];
        const float idx0 = t2.x * 512.f, idx1 = t2.y * 512.f;
        const float i0f = floorf(idx0 + 0.5f), j0f = floorf(idx1 + 0.5f);
        const float wi = idx0 - i0f, wj = idx1 - j0f;
        const int i0 = (int)i0f, j0 = (int)j0f;
        const int mi0 = refl(i0), mi1 = refl(i0 + 1);
        const int mj0 = refl(j0), mj1 = refl(j0 + 1);
        const int ilo = min(mi0, mi1), jlo = min(mj0, mj1);
        const bool sr = mi0 > mi1, sc = mj0 > mj1;   // |mi0-mi1| == |mj0-mj1| == 1 always
        const float* srcb = img + b * (IMW * IMW);

        int cc[12], R[12];
#pragma unroll
        for (int c = 0; c < 12; ++c) cc[c] = refl(jlo - 5 + c);
#pragma unroll
        for (int r = 0; r < 12; ++r) R[r] = refl(ilo - 5 + r) * IMW;

        float A_lo = 0.f, A_hi = 0.f, B_lo = 0.f, B_hi = 0.f;
#pragma unroll
        for (int r = 0; r < 12; ++r) {
            const float* base = srcb + R[r];
            float lo = 0.f, hi = 0.f;
#pragma unroll
            for (int c = 0; c < 12; ++c) {
                const float v = base[cc[c]];
                if (c < 11) lo = fmaf(KW[c], v, lo);       // H(row_r, jlo)
                if (c > 0) hi = fmaf(KW[c - 1], v, hi);    // H(row_r, jlo+1)
            }
            if (r < 11) { A_lo = fmaf(KW[r], lo, A_lo); B_lo = fmaf(KW[r], hi, B_lo); }
            if (r > 0)  { A_hi = fmaf(KW[r - 1], lo, A_hi); B_hi = fmaf(KW[r - 1], hi, B_hi); }
        }
        const float yA  = sr ? A_hi : A_lo;   // blurred (mi0, jlo)
        const float yA1 = sr ? A_lo : A_hi;   // blurred (mi1, jlo)
        const float yB  = sr ? B_hi : B_lo;   // blurred (mi0, jlo+1)
        const float yB1 = sr ? B_lo : B_hi;   // blurred (mi1, jlo+1)
        const float y00 = sc ? yB : yA;
        const float y01 = sc ? yA : yB;
        const float y10 = sc ? yB1 : yA1;
        local = 0.5f * ((1.f - wi) * y00 + wi * y10 + (1.f - wj) * y00 + wj * y01);
    }

    // ---- block reduction (2 waves), plain store of this block's partial ----
    for (int o = 32; o; o >>= 1) local += __shfl_down(local, o, 64);
    if ((tid & 63) == 0) red[tid >> 6] = local;
    __syncthreads();
    if (tid == 0) partials[bx] = red[0] + red[1];
}

// Finalize: slots [0,8)=dist sums (ordered + self), [8,264)=gather intensity sums
__global__ __launch_bounds__(256)
void finalize(const float* __restrict__ partials, float* __restrict__ out) {
    const int tid = threadIdx.x;
    float sg = 0.f, sd = 0.f;
    for (int i = tid; i < TOTAL_BLOCKS; i += 256) {
        const float v = partials[i];
        if (i < DIST_BLOCKS) sd += v; else sg += v;
    }
    for (int o = 32; o; o >>= 1) {
        sg += __shfl_down(sg, o, 64);
        sd += __shfl_down(sd, o, 64);
    }
    __shared__ float rg[4], rd[4];
    if ((tid & 63) == 0) { rg[tid >> 6] = sg; rd[tid >> 6] = sd; }
    __syncthreads();
    if (tid == 0) {
        const double Sd = (double)(rd[0] + rd[1] + rd[2] + rd[3]);  // max(0.05-d,0): ordered + self
        const double S1 = (double)(rg[0] + rg[1] + rg[2] + rg[3]);  // sum of intensities
        // upper-pair sum = (Sd - 32768*0.05)/2 ; dp = that / (8 * 4096*4095/2)
        const double dp = (Sd - 1638.4) / 134184960.0;
        const double il = 255.0 - S1 / 32768.0;
        out[0] = (float)(dp + il);
    }
}

extern "C" void kernel_launch(void* const* d_in, const int* in_sizes, int n_in,
                              void* d_out, int out_size, void* d_ws, size_t ws_size,
                              hipStream_t stream) {
    const float* trace = (const float*)d_in[0];
    const float* img = (const float*)d_in[1];
    float* partials = (float*)d_ws;
    float* out = (float*)d_out;

    fused_compute<<<TOTAL_BLOCKS, BS, 0, stream>>>(trace, img, partials);
    finalize<<<1, 256, 0, stream>>>(partials, out);
}

// Round 7
// 94.758 us; speedup vs baseline: 3.1556x; 3.1556x over previous
//
#include <hip/hip_runtime.h>

#define IMW 512
#define NP 4096

#define NROW 20                        // y-rows of width 0.05
#define DIST_BLOCKS 160                // 8 batches x 20 rows
#define GATHER_BLOCKS 256              // 32768 points, 2 threads/point, 128 pts/block
#define TOTAL_BLOCKS (DIST_BLOCKS + GATHER_BLOCKS)
#define BS 256

// Gaussian kernel, sigma = 0.3*((11-1)*0.5 - 1) + 0.8 = 2.0, normalized (f64-accurate, rounded to f32)
__device__ constexpr float KW[11] = {
    0.00881223f, 0.02714359f, 0.06511407f, 0.12164908f, 0.17699836f,
    0.20056542f, 0.17699836f, 0.12164908f, 0.06511407f, 0.02714359f, 0.00881223f};

// reflect map: valid for r in [-5, 517]; matches both the blur pad and the intensity pad
__device__ __forceinline__ int refl(int r) {
    r = r < 0 ? -r : r;
    return r > 511 ? 1022 - r : r;
}

// blocks [0,160): dist-push, one (batch,y-row) per block: band = rows r-1..r+1 in LDS,
//                 each thread tests its center points against the whole band (uniform bound,
//                 broadcast LDS reads). Superset band is exact: contributing pairs have row-diff<=1.
// blocks [160,416): intensity gather w/ inline row-major 2D blur, 2 threads per point.
__global__ __launch_bounds__(BS)
void fused_compute(const float* __restrict__ trace, const float* __restrict__ img,
                   float* __restrict__ partials) {
    const int tid = threadIdx.x;
    const int bx = blockIdx.x;
    const int lane = tid & 63;

    __shared__ __align__(16) char smem[49184];
    float2* band = (float2*)smem;                 // 32768 B (worst-case whole batch)
    int* cidx = (int*)(smem + 32768);             // 16384 B (band positions of centers)
    int* cnts = (int*)(smem + 49152);             // [0]=bandcnt, [1]=centcnt
    float* red = (float*)(smem + 49160);          // 4 floats

    float local;

    if (bx < DIST_BLOCKS) {
        // ---- dist push: batch b, y-row row ----
        const int b = bx / NROW, row = bx - b * NROW;
        const float2* tb = (const float2*)(trace + b * NP * 2);
        if (tid == 0) { cnts[0] = 0; cnts[1] = 0; }
        __syncthreads();
        // stream batch, keep band rows [row-1, row+1]; wave-ballot compaction (1 atomic/wave)
        for (int k = tid; k < NP; k += BS) {
            const float2 pt = tb[k];
            const int cy = min((int)(pt.y * 20.f), NROW - 1);
            const bool inb = (cy >= row - 1) && (cy <= row + 1);
            const bool isc = (cy == row);
            const unsigned long long mb = __ballot(inb);
            const unsigned long long pre = mb & ((1ull << lane) - 1ull);
            int base = 0;
            if (lane == 0) base = atomicAdd(&cnts[0], __popcll(mb));
            base = __shfl(base, 0, 64);
            const int pos = base + __popcll(pre);
            if (inb) band[pos] = pt;
            const unsigned long long mc = __ballot(isc);
            int cbase = 0;
            if (lane == 0) cbase = atomicAdd(&cnts[1], __popcll(mc));
            cbase = __shfl(cbase, 0, 64);
            if (isc) cidx[cbase + __popcll(mc & ((1ull << lane) - 1ull))] = pos;
        }
        __syncthreads();
        const int nb = cnts[0], nc = cnts[1];
        // each thread: its center points vs the whole band (broadcast reads, uniform bound)
        float s = 0.f;
        for (int c = tid; c < nc; c += BS) {
            const float2 p = band[cidx[c]];
            float acc = 0.f;
            for (int q = 0; q < nb; ++q) {
                const float2 o = band[q];
                const float dx = p.x - o.x, dy = p.y - o.y;
                const float d2 = fmaf(dx, dx, dy * dy);
                // self contributes exactly 0.05 once; unordered pairs twice (here + partner row)
                acc += (d2 < 0.0025f) ? (0.05f - __builtin_amdgcn_sqrtf(d2)) : 0.f;
            }
            s += acc;
        }
        local = s;
    } else {
        // ---- intensity gather: 2 threads per point (rows 0-5 / 6-11) ----
        const int g = bx - DIST_BLOCKS;
        const int half = tid & 1;
        const int p = g * 128 + (tid >> 1);        // [0, 32768)
        const int b = p >> 12;
        const float2 t2 = ((const float2*)trace)[b * NP + (p & (NP - 1))];
        const float idx0 = t2.x * 512.f, idx1 = t2.y * 512.f;
        const float i0f = floorf(idx0 + 0.5f), j0f = floorf(idx1 + 0.5f);
        const float wi = idx0 - i0f, wj = idx1 - j0f;
        const int i0 = (int)i0f, j0 = (int)j0f;
        const int mi0 = refl(i0), mi1 = refl(i0 + 1);
        const int mj0 = refl(j0), mj1 = refl(j0 + 1);
        const int ilo = min(mi0, mi1), jlo = min(mj0, mj1);
        const bool sr = mi0 > mi1, sc = mj0 > mj1;   // |mi0-mi1| == |mj0-mj1| == 1 always
        const float* srcb = img + b * (IMW * IMW);

        int cc[12];
#pragma unroll
        for (int c = 0; c < 12; ++c) cc[c] = refl(jlo - 5 + c);

        float A_lo = 0.f, A_hi = 0.f, B_lo = 0.f, B_hi = 0.f;
#pragma unroll
        for (int rr = 0; rr < 6; ++rr) {
            const int r = half ? rr + 6 : rr;
            const float* base = srcb + refl(ilo - 5 + r) * IMW;
            float lo = 0.f, hi = 0.f;
#pragma unroll
            for (int c = 0; c < 12; ++c) {
                const float v = base[cc[c]];
                if (c < 11) lo = fmaf(KW[c], v, lo);       // H(row_r, jlo)
                if (c > 0) hi = fmaf(KW[c - 1], v, hi);    // H(row_r, jlo+1)
            }
            // vertical weights, compile-time constants selected by uniform `half`
            const float wlo = half ? (rr < 5 ? KW[rr + 6] : 0.f) : KW[rr];
            const float whi = half ? KW[rr + 5] : (rr > 0 ? KW[rr - 1] : 0.f);
            A_lo = fmaf(wlo, lo, A_lo);
            A_hi = fmaf(whi, lo, A_hi);
            B_lo = fmaf(wlo, hi, B_lo);
            B_hi = fmaf(whi, hi, B_hi);
        }
        // combine the two halves of each point (lanes 2k, 2k+1)
        A_lo += __shfl_xor(A_lo, 1, 64);
        A_hi += __shfl_xor(A_hi, 1, 64);
        B_lo += __shfl_xor(B_lo, 1, 64);
        B_hi += __shfl_xor(B_hi, 1, 64);
        const float yA  = sr ? A_hi : A_lo;   // blurred (mi0, jlo)
        const float yA1 = sr ? A_lo : A_hi;   // blurred (mi1, jlo)
        const float yB  = sr ? B_hi : B_lo;   // blurred (mi0, jlo+1)
        const float yB1 = sr ? B_lo : B_hi;   // blurred (mi1, jlo+1)
        const float y00 = sc ? yB : yA;
        const float y01 = sc ? yA : yB;
        const float y10 = sc ? yB1 : yA1;
        const float inten = 0.5f * ((1.f - wi) * y00 + wi * y10 + (1.f - wj) * y00 + wj * y01);
        local = (half == 0) ? inten : 0.f;
    }

    // ---- block reduction (4 waves), plain store of this block's partial ----
    for (int o = 32; o; o >>= 1) local += __shfl_down(local, o, 64);
    __syncthreads();                       // smem reuse barrier (band phase done)
    if ((tid & 63) == 0) red[tid >> 6] = local;
    __syncthreads();
    if (tid == 0) partials[bx] = red[0] + red[1] + red[2] + red[3];
}

// Finalize: slots [0,160)=dist sums (ordered + self), [160,416)=gather intensity sums
__global__ __launch_bounds__(256)
void finalize(const float* __restrict__ partials, float* __restrict__ out) {
    const int tid = threadIdx.x;
    float sg = 0.f, sd = 0.f;
    for (int i = tid; i < TOTAL_BLOCKS; i += 256) {
        const float v = partials[i];
        if (i < DIST_BLOCKS) sd += v; else sg += v;
    }
    for (int o = 32; o; o >>= 1) {
        sg += __shfl_down(sg, o, 64);
        sd += __shfl_down(sd, o, 64);
    }
    __shared__ float rg[4], rd[4];
    if ((tid & 63) == 0) { rg[tid >> 6] = sg; rd[tid >> 6] = sd; }
    __syncthreads();
    if (tid == 0) {
        const double Sd = (double)(rd[0] + rd[1] + rd[2] + rd[3]);  // max(0.05-d,0): ordered + self
        const double S1 = (double)(rg[0] + rg[1] + rg[2] + rg[3]);  // sum of intensities
        // upper-pair sum = (Sd - 32768*0.05)/2 ; dp = that / (8 * 4096*4095/2)
        const double dp = (Sd - 1638.4) / 134184960.0;
        const double il = 255.0 - S1 / 32768.0;
        out[0] = (float)(dp + il);
    }
}

extern "C" void kernel_launch(void* const* d_in, const int* in_sizes, int n_in,
                              void* d_out, int out_size, void* d_ws, size_t ws_size,
                              hipStream_t stream) {
    const float* trace = (const float*)d_in[0];
    const float* img = (const float*)d_in[1];
    float* partials = (float*)d_ws;
    float* out = (float*)d_out;

    fused_compute<<<TOTAL_BLOCKS, BS, 0, stream>>>(trace, img, partials);
    finalize<<<1, 256, 0, stream>>>(partials, out);
}